// Round 13
// baseline (253.797 us; speedup 1.0000x reference)
//
#include <hip/hip_runtime.h>
#include <hip/hip_bf16.h>

#define NB 64
#define H0 224
#define W0 224
#define C1 24
#define C2 48
#define H1 112
#define W1 112
#define H2 56
#define W2 56
#define EPSV 1e-5f

// ws layout (float offsets)
#define WS_STATS1   0                       // 8 x (24+24) = 384
#define WS_STATS2   432                     // 8 x (48+48) = 768
#define WS_FEAT     1296                    // 64*48 = 3072
#define WS_B2       4368                    // 13824 fp16 = 6912 float slots (wave-linear w2 frags)
#define WS_X2       11280                   // pool_t fp16 k-blocked [2352 g][64 b][64]
#define WS_FWT      (WS_X2 + 4818944)       // fwt fp16 k-blocked [2352 g][48 o][64]
#define WS_X1       9645072                 // fp16 pooled PRE-BN conv1 max, ch-last [64][112][112][24]
#define WS_NEED_BIG ((size_t)(WS_X1 + 9633792) * 4)   // 77,115,456 B
#define OUT0_ELEMS  (NB*H0*W0)

typedef _Float16 v8h __attribute__((ext_vector_type(8)));   // 8 fp16 (4 VGPRs)
typedef float    v4f __attribute__((ext_vector_type(4)));   // MFMA acc / float4 loads

static __device__ __forceinline__ unsigned short f2h(float v) {
    _Float16 h = (_Float16)v;
    unsigned short us;
    __builtin_memcpy(&us, &h, 2);
    return us;
}

// ================= BIG-WS PATH =================
// K1 v2 (merged): heterogeneous grid 896+1176.
//  bid <  896: conv1+pool+stats, FULL-WIDTH tile: 8 pooled rows x 112 cols (input rows 904B contiguous).
//              4 waves x 6 channels (SGPR weights); outputs staged in 2 chunks of 448 positions.
//  bid >= 896: fw-transpose prep block; blocks p<54 additionally zero stats2/feat + build w2 frags.
__global__ __launch_bounds__(256) void k_stats_prep2(
    const float* __restrict__ x, const float* __restrict__ w1, const float* __restrict__ b1,
    const float* __restrict__ w2, const float* __restrict__ fw,
    float* __restrict__ ws, _Float16* __restrict__ x1g, _Float16* __restrict__ fwt)
{
    __shared__ __align__(16) unsigned char smem[39808];   // 4 blocks/CU (159.2 KB)
    const int tid = threadIdx.x;
    const int bid = blockIdx.x;

    if (bid >= 896) {
        // -------- prep path (unchanged) --------
        _Float16 (*T)[136] = (_Float16(*)[136])smem;
        const int p = bid - 896;                             // 0..1175
        if (p < 54) {
            int t = p * 256 + tid;
            if (t >= 432 && t < WS_B2) ws[t] = 0.f;          // zero stats2 + feat
            if (t < 13824) {
                int e = t & 7;
                int l = (t >> 3) & 63;
                int g = t >> 9;
                int q = l >> 4, ml = l & 15;
                int kp = g / 3, nt = g % 3;
                int ic = q * 8 + e;
                int oc = nt * 16 + ml;
                float v = (ic < C1) ? w2[(oc * C1 + ic) * 9 + kp] : 0.f;
                ((_Float16*)(ws + WS_B2))[t] = (_Float16)v;
            }
        }
        const int kb = p * 128;
#pragma unroll
        for (int t3 = 0; t3 < 6; t3++) {
            int li = tid + 256 * t3;
            int o = li >> 5, k4 = li & 31;
            float4 v = *(const float4*)&fw[(long)o * 150528 + kb + 4 * k4];
            T[o][4 * k4 + 0] = (_Float16)v.x;
            T[o][4 * k4 + 1] = (_Float16)v.y;
            T[o][4 * k4 + 2] = (_Float16)v.z;
            T[o][4 * k4 + 3] = (_Float16)v.w;
        }
        __syncthreads();
        uint4* dst = (uint4*)&fwt[(long)kb * 48];
#pragma unroll
        for (int t3 = 0; t3 < 3; t3++) {
            int u = tid + 256 * t3;
            int gg = u / 384;
            int rem = u % 384;
            int o = rem >> 3;
            int k8 = (rem & 7) * 8;
            dst[u] = *(const uint4*)&T[o][gg * 64 + k8];
        }
        return;
    }

    // -------- stats path: full-width tile --------
    float (*xt)[226] = (float(*)[226])smem;                      // 18 x 226 f32 = 16,272 B
    unsigned int (*outt)[13] = (unsigned int(*)[13])(smem + 16272); // 448 x 13 u32 = 23,296 B
    float* sred = (float*)(smem + 39568);                        // 192 B

    const int b = bid / 14;
    const int rg = bid % 14;                     // pooled row group (8 rows each)
    const int iy0 = 16 * rg - 1;                 // input row base (18 rows)
    const float* xb = x + b * (H0 * W0);

    // stage 18 x 226 input tile: rows are 904B contiguous reads
    for (int li = tid; li < 18 * 226; li += 256) {
        int ry = li / 226, rx = li % 226;
        int gy = iy0 + ry, gx = rx - 1;
        bool ok = (gy >= 0) & (gy < H0) & (gx >= 0) & (gx < W0);
        xt[ry][rx] = ok ? xb[gy * W0 + gx] : 0.f;
    }

    const int wid = tid >> 6;
    const int lane = tid & 63;
    const int c0 = wid * 6;

    const int c0s = __builtin_amdgcn_readfirstlane(c0);
    const float* __restrict__ wps = w1 + c0s * 9;
    float wr[54], br[6];
#pragma unroll
    for (int k = 0; k < 54; k++) wr[k] = wps[k];
#pragma unroll
    for (int c = 0; c < 6; c++) br[c] = b1[c0s + c];

    __syncthreads();

    float s[6] = {0.f, 0.f, 0.f, 0.f, 0.f, 0.f};
    float q[6] = {0.f, 0.f, 0.f, 0.f, 0.f, 0.f};

#pragma unroll
    for (int chunk = 0; chunk < 2; chunk++) {
        // compute 448 positions (4 pooled rows x 112 cols), 7 per lane
#pragma unroll
        for (int pp = 0; pp < 7; pp++) {
            const int pos = lane + 64 * pp;
            const int prl = pos / 112, pc = pos % 112;
            const int xr0 = 8 * chunk + 2 * prl;
            float patch[16];
#pragma unroll
            for (int i2 = 0; i2 < 4; i2++)
#pragma unroll
                for (int j2 = 0; j2 < 4; j2++)
                    patch[i2 * 4 + j2] = xt[xr0 + i2][2 * pc + j2];

            unsigned int pk[3];
#pragma unroll
            for (int cp = 0; cp < 3; cp++) {
                unsigned int pv = 0;
#pragma unroll
                for (int h = 0; h < 2; h++) {
                    int c = 2 * cp + h;
                    float m4 = -1e30f;
#pragma unroll
                    for (int sy = 0; sy < 2; sy++)
#pragma unroll
                        for (int sx = 0; sx < 2; sx++) {
                            float a = br[c];
#pragma unroll
                            for (int ky = 0; ky < 3; ky++)
#pragma unroll
                                for (int kx = 0; kx < 3; kx++)
                                    a = fmaf(patch[(sy + ky) * 4 + (sx + kx)], wr[c * 9 + ky * 3 + kx], a);
                            s[c] += a;
                            q[c] = fmaf(a, a, q[c]);
                            m4 = fmaxf(m4, a);
                        }
                    pv |= ((unsigned int)f2h(m4)) << (16 * h);
                }
                pk[cp] = pv;
            }
            outt[pos][wid * 3 + 0] = pk[0];
            outt[pos][wid * 3 + 1] = pk[1];
            outt[pos][wid * 3 + 2] = pk[2];
        }
        __syncthreads();     // outt complete

        // coalesced uint4 store: 1344 uint4 (448 pos x 48B)
        for (int u = tid; u < 1344; u += 256) {
            int pos = u / 3, prt = u % 3;
            int prl = pos / 112, pc = pos % 112;
            int py = 8 * rg + 4 * chunk + prl;
            long p = (long)(b * H1 + py) * W1 + pc;
            uint4 v;
            v.x = outt[pos][4 * prt + 0];
            v.y = outt[pos][4 * prt + 1];
            v.z = outt[pos][4 * prt + 2];
            v.w = outt[pos][4 * prt + 3];
            *(uint4*)(x1g + p * C1 + prt * 8) = v;
        }
        __syncthreads();     // outt reads done before chunk-1 overwrites
    }

    // stats reduce once per block
#pragma unroll
    for (int c = 0; c < 6; c++) {
#pragma unroll
        for (int off = 32; off > 0; off >>= 1) {
            s[c] += __shfl_down(s[c], off, 64);
            q[c] += __shfl_down(q[c], off, 64);
        }
    }
    if (lane == 0) {
#pragma unroll
        for (int c = 0; c < 6; c++) {
            sred[c0 + c] = s[c];
            sred[C1 + c0 + c] = q[c];
        }
    }
    __syncthreads();
    if (tid < 2 * C1) {
        atomicAdd(&ws[WS_STATS1 + (bid & 7) * 2 * C1 + tid], sred[tid]);
    }
}

// K2 v6: persistent conv2 MFMA, 16x16 tiles (4 rows/wave). B in 108 VGPRs loaded once;
// x1 dbuf LDS 2x18x18x32; BN2 stats in regs; pool_t fp16 k-blocked output. Grid 512.
__global__ __launch_bounds__(256, 2) void k_conv2_fused6(
    const _Float16* __restrict__ x1g, const _Float16* __restrict__ bpp,
    const float* __restrict__ g1, const float* __restrict__ bb1,
    const float* __restrict__ b2,
    float* __restrict__ ws, unsigned int* __restrict__ pooltu)
{
    __shared__ __align__(16) _Float16 x1t[2][18][18][32];
    __shared__ float alds[C1], bflds[C1];
    __shared__ float sred[2 * C2];

    const int tid = threadIdx.x;
    const int w = tid >> 6;
    const int lane = tid & 63;
    const int ml = lane & 15;
    const int qq = lane >> 4;

    v8h B[9][3];
#pragma unroll
    for (int kp = 0; kp < 9; kp++)
#pragma unroll
        for (int nt = 0; nt < 3; nt++)
            B[kp][nt] = *(const v8h*)&bpp[((kp * 3 + nt) * 64 + lane) * 8];

    if (tid < C1) {
        float s = 0.f, q = 0.f;
#pragma unroll
        for (int i = 0; i < 8; i++) {
            s += ws[WS_STATS1 + i * 2 * C1 + tid];
            q += ws[WS_STATS1 + i * 2 * C1 + C1 + tid];
        }
        const float N = (float)(NB * H0 * W0);
        float m = s / N;
        float v = q / N - m * m;
        float a = g1[tid] / sqrtf(v + EPSV);
        alds[tid] = a;
        bflds[tid] = bb1[tid] - m * a;
    }
    if (tid < 2 * C2) sred[tid] = 0.f;

    {
        v8h z8;
#pragma unroll
        for (int e = 0; e < 8; e++) z8[e] = (_Float16)0.f;
        for (int li = tid; li < 2 * 18 * 18; li += 256) {
            int bu = li / 324, pos = li % 324;
            *(v8h*)&x1t[bu][pos / 18][pos % 18][24] = z8;
        }
    }

    float bias[3] = {b2[ml], b2[16 + ml], b2[32 + ml]};

    int spart[4], spr[4], spc[4]; bool sv[4];
#pragma unroll
    for (int s4 = 0; s4 < 4; s4++) {
        int li = tid + s4 * 256;
        sv[s4] = li < 972;
        int part = li % 3;
        int pos = li / 3;
        spart[s4] = part;
        spr[s4] = pos / 18;
        spc[s4] = pos % 18;
    }

    const int nb = gridDim.x;
    const int NTILE = 3136;
    int qn = NTILE / nb, rn = NTILE % nb;
    int start = (blockIdx.x < rn) ? blockIdx.x * (qn + 1)
                                  : rn * (qn + 1) + (blockIdx.x - rn) * qn;
    int cnt = (blockIdx.x < rn) ? qn + 1 : qn;

    float svacc[3] = {0.f, 0.f, 0.f}, qvacc[3] = {0.f, 0.f, 0.f};

    v8h raw[4];
    bool inb_n[4];
    {
        int t = start;
        int tb = t / 49, rem = t % 49;
        int ty = (rem / 7) * 16, txx = (rem % 7) * 16;
#pragma unroll
        for (int s4 = 0; s4 < 4; s4++) {
#pragma unroll
            for (int e = 0; e < 8; e++) raw[s4][e] = (_Float16)0.f;
            int gy = ty - 1 + spr[s4], gx = txx - 1 + spc[s4];
            inb_n[s4] = sv[s4] & (gy >= 0) & (gy < H1) & (gx >= 0) & (gx < W1);
            if (inb_n[s4])
                raw[s4] = *(const v8h*)&x1g[((tb * H1 + gy) * W1 + gx) * C1 + spart[s4] * 8];
        }
    }
    __syncthreads();

#pragma unroll
    for (int s4 = 0; s4 < 4; s4++) {
        if (sv[s4]) {
            v8h r8;
            if (inb_n[s4]) {
#pragma unroll
                for (int e = 0; e < 8; e++) {
                    int c = spart[s4] * 8 + e;
                    float vv = fmaxf(fmaf((float)raw[s4][e], alds[c], bflds[c]), 0.f);
                    r8[e] = (_Float16)vv;
                }
            } else {
#pragma unroll
                for (int e = 0; e < 8; e++) r8[e] = (_Float16)0.f;
            }
            *(v8h*)&x1t[0][spr[s4]][spc[s4]][spart[s4] * 8] = r8;
        }
    }
    __syncthreads();

    for (int it = 0; it < cnt; it++) {
        const int cur = it & 1;
        const int t = start + it;
        const int tb = t / 49, rem = t % 49;
        const int ty = (rem / 7) * 16, txx = (rem % 7) * 16;

        const bool haveNext = (it + 1 < cnt);
        if (haveNext) {
            int t2 = t + 1;
            int nb2 = t2 / 49, rem2 = t2 % 49;
            int ny = (rem2 / 7) * 16, nx = (rem2 % 7) * 16;
#pragma unroll
            for (int s4 = 0; s4 < 4; s4++) {
#pragma unroll
                for (int e = 0; e < 8; e++) raw[s4][e] = (_Float16)0.f;
                int gy = ny - 1 + spr[s4], gx = nx - 1 + spc[s4];
                inb_n[s4] = sv[s4] & (gy >= 0) & (gy < H1) & (gx >= 0) & (gx < W1);
                if (inb_n[s4])
                    raw[s4] = *(const v8h*)&x1g[((nb2 * H1 + gy) * W1 + gx) * C1 + spart[s4] * 8];
            }
        }

        v4f acc[4][3];
#pragma unroll
        for (int mt = 0; mt < 4; mt++)
#pragma unroll
            for (int nt = 0; nt < 3; nt++)
                acc[mt][nt] = (v4f){0.f, 0.f, 0.f, 0.f};

#pragma unroll
        for (int kp = 0; kp < 9; kp++) {
            const int ky = kp / 3, kx = kp % 3;
#pragma unroll
            for (int mt = 0; mt < 4; mt++) {
                const int r = 4 * w + mt;
                v8h a = *(const v8h*)&x1t[cur][r + ky][ml + kx][qq * 8];
                acc[mt][0] = __builtin_amdgcn_mfma_f32_16x16x32_f16(a, B[kp][0], acc[mt][0], 0, 0, 0);
                acc[mt][1] = __builtin_amdgcn_mfma_f32_16x16x32_f16(a, B[kp][1], acc[mt][1], 0, 0, 0);
                acc[mt][2] = __builtin_amdgcn_mfma_f32_16x16x32_f16(a, B[kp][2], acc[mt][2], 0, 0, 0);
            }
        }

#pragma unroll
        for (int nt = 0; nt < 3; nt++) {
            int oc = nt * 16 + ml;
            float z[4][4];
#pragma unroll
            for (int mt = 0; mt < 4; mt++)
#pragma unroll
                for (int rg = 0; rg < 4; rg++) {
                    float val = acc[mt][nt][rg] + bias[nt];
                    z[mt][rg] = val;
                    svacc[nt] += val;
                    qvacc[nt] = fmaf(val, val, qvacc[nt]);
                }
#pragma unroll
            for (int h = 0; h < 2; h++) {
                int py = (ty >> 1) + 2 * w + h;
                float m0 = fmaxf(fmaxf(z[2 * h][0], z[2 * h][1]),
                                 fmaxf(z[2 * h + 1][0], z[2 * h + 1][1]));
                float m1 = fmaxf(fmaxf(z[2 * h][2], z[2 * h][3]),
                                 fmaxf(z[2 * h + 1][2], z[2 * h + 1][3]));
                int px0 = (txx >> 1) + qq * 2;
                int k = oc * 3136 + py * W2 + px0;
                unsigned int pk2 = (unsigned int)f2h(m0) | ((unsigned int)f2h(m1) << 16);
                pooltu[(((k >> 6) * NB + tb) << 5) + ((k & 63) >> 1)] = pk2;
            }
        }

        if (haveNext) {
#pragma unroll
            for (int s4 = 0; s4 < 4; s4++) {
                if (sv[s4]) {
                    v8h r8;
                    if (inb_n[s4]) {
#pragma unroll
                        for (int e = 0; e < 8; e++) {
                            int c = spart[s4] * 8 + e;
                            float vv = fmaxf(fmaf((float)raw[s4][e], alds[c], bflds[c]), 0.f);
                            r8[e] = (_Float16)vv;
                        }
                    } else {
#pragma unroll
                        for (int e = 0; e < 8; e++) r8[e] = (_Float16)0.f;
                    }
                    *(v8h*)&x1t[cur ^ 1][spr[s4]][spc[s4]][spart[s4] * 8] = r8;
                }
            }
        }
        __syncthreads();
    }

#pragma unroll
    for (int nt = 0; nt < 3; nt++) {
        float sv2 = svacc[nt], qv = qvacc[nt];
        sv2 += __shfl_xor(sv2, 16, 64); qv += __shfl_xor(qv, 16, 64);
        sv2 += __shfl_xor(sv2, 32, 64); qv += __shfl_xor(qv, 32, 64);
        if (qq == 0) {
            atomicAdd(&sred[nt * 16 + ml], sv2);
            atomicAdd(&sred[C2 + nt * 16 + ml], qv);
        }
    }
    __syncthreads();
    if (tid < 2 * C2) {
        atomicAdd(&ws[WS_STATS2 + (blockIdx.x & 7) * 2 * C2 + tid], sred[tid]);
    }
}

// K3 v6: MFMA fconv on linear fp16 streams; atomicAdd directly into feat.
__global__ __launch_bounds__(256) void k_fconv6(
    const unsigned int* __restrict__ pooltu, const _Float16* __restrict__ fwt,
    const float* __restrict__ ws, const float* __restrict__ g2, const float* __restrict__ bb2,
    float* __restrict__ feat)
{
    __shared__ __align__(16) _Float16 fwh[48][136];
    __shared__ __align__(16) _Float16 x2h[64][136];
    __shared__ float csh[2 * C2];

    const int tid = threadIdx.x;
    const int bx = blockIdx.x;

    const uint4* fsrc = (const uint4*)fwt + (long)bx * 768;
    const uint4* psrc = (const uint4*)pooltu + (long)bx * 1024;
    uint4 fr[3], pr[4];
#pragma unroll
    for (int t3 = 0; t3 < 3; t3++) fr[t3] = fsrc[tid + 256 * t3];
#pragma unroll
    for (int t4 = 0; t4 < 4; t4++) pr[t4] = psrc[tid + 256 * t4];

    if (tid < C2) {
        int c = tid;
        float s = 0.f, q = 0.f;
#pragma unroll
        for (int i = 0; i < 8; i++) {
            s += ws[WS_STATS2 + i * 2 * C2 + c];
            q += ws[WS_STATS2 + i * 2 * C2 + C2 + c];
        }
        const float N = (float)(NB * H1 * W1);
        float m = s / N;
        float v = q / N - m * m;
        float a = g2[c] / sqrtf(v + EPSV);
        csh[c] = a;
        csh[C2 + c] = bb2[c] - m * a;
    }
    __syncthreads();

#pragma unroll
    for (int t3 = 0; t3 < 3; t3++) {
        int li = tid + 256 * t3;
        int gg = li / 384;
        int o = (li % 384) / 8;
        int kin = (li & 7) * 8;
        *(uint4*)&fwh[o][gg * 64 + kin] = fr[t3];
    }
    const int c0 = (2 * bx) / 49, c1 = (2 * bx + 1) / 49;
    const float a0 = csh[c0], bf0 = csh[C2 + c0];
    const float a1 = csh[c1], bf1 = csh[C2 + c1];
#pragma unroll
    for (int t4 = 0; t4 < 4; t4++) {
        int li = tid + 256 * t4;
        int gg = li >> 9;
        int b = (li & 511) >> 3;
        int kin = (li & 7) * 8;
        float aa = gg ? a1 : a0;
        float bb = gg ? bf1 : bf0;
        union { uint4 u; v8h h; } cv;
        cv.u = pr[t4];
        v8h r8;
#pragma unroll
        for (int e = 0; e < 8; e++)
            r8[e] = (_Float16)fmaxf(fmaf((float)cv.h[e], aa, bb), 0.f);
        *(v8h*)&x2h[b][gg * 64 + kin] = r8;
    }
    __syncthreads();

    const int w = tid >> 6;
    const int lane = tid & 63;
    const int ml = lane & 15;
    const int qq = lane >> 4;

    v4f acc[3];
#pragma unroll
    for (int ot = 0; ot < 3; ot++) acc[ot] = (v4f){0.f, 0.f, 0.f, 0.f};

#pragma unroll
    for (int ks = 0; ks < 4; ks++) {
        v8h a = *(const v8h*)&x2h[w * 16 + ml][ks * 32 + qq * 8];
#pragma unroll
        for (int ot = 0; ot < 3; ot++) {
            v8h bb = *(const v8h*)&fwh[ot * 16 + ml][ks * 32 + qq * 8];
            acc[ot] = __builtin_amdgcn_mfma_f32_16x16x32_f16(a, bb, acc[ot], 0, 0, 0);
        }
    }

#pragma unroll
    for (int ot = 0; ot < 3; ot++)
#pragma unroll
        for (int rg = 0; rg < 4; rg++)
            atomicAdd(&feat[(w * 16 + qq * 4 + rg) * C2 + ot * 16 + ml], acc[ot][rg]);
}

// K4 (merged head): grid_sample with wave-local head.
__global__ __launch_bounds__(256) void k_sample4(
    const float* __restrict__ x, const float* __restrict__ feat, const float* __restrict__ fcb,
    const float* __restrict__ l1w, const float* __restrict__ l1b,
    const float* __restrict__ l2w, const float* __restrict__ l2b,
    float* __restrict__ out)
{
    __shared__ float hsh[24];
    __shared__ float th[4];
    const int b = blockIdx.y;
    const int tid = threadIdx.x;
    if (tid < 24) {
        float a = l1b[tid];
#pragma unroll
        for (int o = 0; o < C2; o++)
            a = fmaf(feat[b * C2 + o] + fcb[o], l1w[tid * C2 + o], a);
        hsh[tid] = fmaxf(a, 0.f);
    }
    __syncthreads();
    if (tid < 4) {
        float a = l2b[tid];
#pragma unroll
        for (int jj = 0; jj < 24; jj++) a = fmaf(hsh[jj], l2w[tid * 24 + jj], a);
        th[tid] = a;
        if (blockIdx.x == 0) out[OUT0_ELEMS + tid * NB + b] = a;
    }
    __syncthreads();

    const float tx = th[0], ty = th[1], sc = th[2], an = th[3];
    const float cc = cosf(an), ss = sinf(an);
    const float t00 = sc * cc, t01 = -sc * ss, t10 = sc * ss, t11 = sc * cc;
    const float* xb = x + b * (H0 * W0);

    int idx = (blockIdx.x * 256 + tid) * 2;
    int i = idx / W0, j = idx % W0;
    float ys = (2.f * (float)i + 1.f) / (float)H0 - 1.f;

    float o2[2];
#pragma unroll
    for (int px = 0; px < 2; px++) {
        float xs = (2.f * (float)(j + px) + 1.f) / (float)W0 - 1.f;
        float gx = t00 * xs + t01 * ys + tx;
        float gy = t10 * xs + t11 * ys + ty;
        float ix = ((gx + 1.f) * (float)W0 - 1.f) * 0.5f;
        float iy = ((gy + 1.f) * (float)H0 - 1.f) * 0.5f;
        float x0 = floorf(ix), y0 = floorf(iy);
        float x1f = x0 + 1.f, y1f = y0 + 1.f;
        float wx1 = ix - x0, wx0 = 1.f - wx1;
        float wy1 = iy - y0, wy0 = 1.f - wy1;
        auto tap = [&](float xf, float yf, float wgt) -> float {
            bool valid = (xf >= 0.f) & (xf < (float)W0) & (yf >= 0.f) & (yf < (float)H0);
            int xi = (int)fminf(fmaxf(xf, 0.f), (float)(W0 - 1));
            int yi = (int)fminf(fmaxf(yf, 0.f), (float)(H0 - 1));
            return valid ? xb[yi * W0 + xi] * wgt : 0.f;
        };
        o2[px] = tap(x0, y0, wx0 * wy0) + tap(x1f, y0, wx1 * wy0)
               + tap(x0, y1f, wx0 * wy1) + tap(x1f, y1f, wx1 * wy1);
    }
    *(float2*)&out[(b * H0 + i) * W0 + j] = make_float2(o2[0], o2[1]);
}

// ================= OLD PROVEN PATH (fallback if ws too small) =================
__global__ __launch_bounds__(256) void k_init(const float* __restrict__ w2, float* __restrict__ ws)
{
    int t = blockIdx.x * 256 + threadIdx.x;
    if (t < WS_B2) ws[t] = 0.f;
    if (t < 13824) {
        int e = t & 7;
        int l = (t >> 3) & 63;
        int g = t >> 9;
        int q = l >> 4, ml = l & 15;
        int kp = g / 3, nt = g % 3;
        int ic = q * 8 + e;
        int oc = nt * 16 + ml;
        float v = (ic < C1) ? w2[(oc * C1 + ic) * 9 + kp] : 0.f;
        ((_Float16*)(ws + WS_B2))[t] = (_Float16)v;
    }
}

__global__ __launch_bounds__(256) void k_conv1_stats(
    const float* __restrict__ x, const float* __restrict__ w1, const float* __restrict__ b1,
    float* __restrict__ ws)
{
    float s[C1], q[C1];
#pragma unroll
    for (int c = 0; c < C1; c++) { s[c] = 0.f; q[c] = 0.f; }
    const int NT = gridDim.x * 256;
    const int total = NB * H0 * W0;
    for (int p = blockIdx.x * 256 + threadIdx.x; p < total; p += NT) {
        int b = p / (H0 * W0);
        int r = p % (H0 * W0);
        int y = r / W0;
        int xx = r % W0;
        const float* xb = x + b * (H0 * W0);
        float patch[9];
#pragma unroll
        for (int dy = 0; dy < 3; dy++)
#pragma unroll
            for (int dx = 0; dx < 3; dx++) {
                int yy = y + dy - 1, xc = xx + dx - 1;
                bool ok = (yy >= 0) & (yy < H0) & (xc >= 0) & (xc < W0);
                patch[dy * 3 + dx] = ok ? xb[yy * W0 + xc] : 0.f;
            }
#pragma unroll
        for (int c = 0; c < C1; c++) {
            const float* wp = w1 + c * 9;
            float a = b1[c];
#pragma unroll
            for (int k = 0; k < 9; k++) a = fmaf(patch[k], wp[k], a);
            s[c] += a;
            q[c] = fmaf(a, a, q[c]);
        }
    }
#pragma unroll
    for (int c = 0; c < C1; c++) {
#pragma unroll
        for (int off = 32; off > 0; off >>= 1) {
            s[c] += __shfl_down(s[c], off, 64);
            q[c] += __shfl_down(q[c], off, 64);
        }
    }
    __shared__ float sred[2 * C1];
    if (threadIdx.x < 2 * C1) sred[threadIdx.x] = 0.f;
    __syncthreads();
    if ((threadIdx.x & 63) == 0) {
#pragma unroll
        for (int c = 0; c < C1; c++) {
            atomicAdd(&sred[c], s[c]);
            atomicAdd(&sred[C1 + c], q[c]);
        }
    }
    __syncthreads();
    if (threadIdx.x < 2 * C1) {
        atomicAdd(&ws[WS_STATS1 + (blockIdx.x & 7) * 2 * C1 + threadIdx.x], sred[threadIdx.x]);
    }
}

__global__ __launch_bounds__(256, 2) void k_conv2_fused(
    const float* __restrict__ x, const float* __restrict__ w1, const float* __restrict__ b1,
    const float* __restrict__ g1, const float* __restrict__ bb1,
    const _Float16* __restrict__ bpp, const float* __restrict__ b2,
    float* __restrict__ ws, float* __restrict__ pool)
{
    __shared__ float xt[22][38];
    __shared__ __align__(16) _Float16 x1t[10][18][32];
    __shared__ __align__(16) _Float16 Blds[13824];
    __shared__ float wlds[C1 * 9];
    __shared__ float blds[C1], alds[C1], bflds[C1];
    __shared__ float sred[2 * C2];

    const int tid = threadIdx.x;
    const int b = blockIdx.z;
    const int y0 = blockIdx.y * 8;
    const int x0 = blockIdx.x * 16;
    const float* xb = x + b * (H0 * W0);

    for (int li = tid; li < 13824 / 8; li += 256)
        ((uint4*)Blds)[li] = ((const uint4*)bpp)[li];

    if (tid < C1 * 9) wlds[tid] = w1[tid];
    if (tid < C1) {
        float s = 0.f, q = 0.f;
#pragma unroll
        for (int i = 0; i < 8; i++) {
            s += ws[WS_STATS1 + i * 2 * C1 + tid];
            q += ws[WS_STATS1 + i * 2 * C1 + C1 + tid];
        }
        const float N = (float)(NB * H0 * W0);
        float m = s / N;
        float v = q / N - m * m;
        float a = g1[tid] / sqrtf(v + EPSV);
        blds[tid] = b1[tid];
        alds[tid] = a;
        bflds[tid] = bb1[tid] - m * a;
    }
    if (tid < 2 * C2) sred[tid] = 0.f;

    const int oy0 = 2 * y0 - 3, ox0 = 2 * x0 - 3;
    for (int li = tid; li < 22 * 38; li += 256) {
        int ry = li / 38, rx = li % 38;
        int gy = oy0 + ry, gx = ox0 + rx;
        bool ok = (gy >= 0) & (gy < H0) & (gx >= 0) & (gx < W0);
        xt[ry][rx] = ok ? xb[gy * W0 + gx] : 0.f;
    }
    __syncthreads();

    if (tid < 180) {
        int pr = tid / 18, pc = tid % 18;
        int gy = y0 - 1 + pr, gx = x0 - 1 + pc;
        bool valid = (gy >= 0) & (gy < H1) & (gx >= 0) & (gx < W1);
        float patch[16];
#pragma unroll
        for (int dy = 0; dy < 4; dy++)
#pragma unroll
            for (int dx = 0; dx < 4; dx++)
                patch[dy * 4 + dx] = xt[2 * pr + dy][2 * pc + dx];
        unsigned int* dst = (unsigned int*)&x1t[pr][pc][0];
#pragma unroll
        for (int cp = 0; cp < 12; cp++) {
            unsigned int pk = 0;
#pragma unroll
            for (int h = 0; h < 2; h++) {
                int c = 2 * cp + h;
                float m4 = -1e30f;
#pragma unroll
                for (int py = 0; py < 2; py++)
#pragma unroll
                    for (int px = 0; px < 2; px++) {
                        float a = blds[c];
#pragma unroll
                        for (int ky = 0; ky < 3; ky++)
#pragma unroll
                            for (int kx = 0; kx < 3; kx++)
                                a = fmaf(patch[(py + ky) * 4 + (px + kx)], wlds[c * 9 + ky * 3 + kx], a);
                        m4 = fmaxf(m4, fmaf(a, alds[c], bflds[c]));
                    }
                float v = valid ? fmaxf(m4, 0.f) : 0.f;
                pk |= ((unsigned int)f2h(v)) << (16 * h);
            }
            dst[cp] = pk;
        }
        dst[12] = 0; dst[13] = 0; dst[14] = 0; dst[15] = 0;
    }
    __syncthreads();

    const int w = tid >> 6;
    const int lane = tid & 63;
    const int ml = lane & 15;
    const int q = lane >> 4;

    v4f acc[2][3];
#pragma unroll
    for (int mt = 0; mt < 2; mt++)
#pragma unroll
        for (int nt = 0; nt < 3; nt++)
            acc[mt][nt] = (v4f){0.f, 0.f, 0.f, 0.f};

#pragma unroll
    for (int kp = 0; kp < 9; kp++) {
        const int ky = kp / 3, kx = kp % 3;
        v8h B0 = *(const v8h*)&Blds[((kp * 3 + 0) * 64 + lane) * 8];
        v8h B1 = *(const v8h*)&Blds[((kp * 3 + 1) * 64 + lane) * 8];
        v8h B2 = *(const v8h*)&Blds[((kp * 3 + 2) * 64 + lane) * 8];
#pragma unroll
        for (int mt = 0; mt < 2; mt++) {
            const int r = 2 * w + mt;
            v8h a = *(const v8h*)&x1t[r + ky][ml + kx][q * 8];
            acc[mt][0] = __builtin_amdgcn_mfma_f32_16x16x32_f16(a, B0, acc[mt][0], 0, 0, 0);
            acc[mt][1] = __builtin_amdgcn_mfma_f32_16x16x32_f16(a, B1, acc[mt][1], 0, 0, 0);
            acc[mt][2] = __builtin_amdgcn_mfma_f32_16x16x32_f16(a, B2, acc[mt][2], 0, 0, 0);
        }
    }

#pragma unroll
    for (int nt = 0; nt < 3; nt++) {
        int oc = nt * 16 + ml;
        float bias = b2[oc];
        float z[2][4];
        float sv = 0.f, qv = 0.f;
#pragma unroll
        for (int mt = 0; mt < 2; mt++)
#pragma unroll
            for (int rg = 0; rg < 4; rg++) {
                float val = acc[mt][nt][rg] + bias;
                z[mt][rg] = val;
                sv += val;
                qv = fmaf(val, val, qv);
            }
        sv += __shfl_xor(sv, 16, 64); qv += __shfl_xor(qv, 16, 64);
        sv += __shfl_xor(sv, 32, 64); qv += __shfl_xor(qv, 32, 64);
        if (q == 0) { atomicAdd(&sred[oc], sv); atomicAdd(&sred[C2 + oc], qv); }

        int py = (y0 >> 1) + w;
#pragma unroll
        for (int j = 0; j < 2; j++) {
            float m = fmaxf(fmaxf(z[0][2 * j], z[0][2 * j + 1]),
                            fmaxf(z[1][2 * j], z[1][2 * j + 1]));
            int px = (x0 >> 1) + q * 2 + j;
            pool[((b * C2 + oc) * H2 + py) * W2 + px] = m;
        }
    }
    __syncthreads();
    if (tid < 2 * C2) {
        int cp = (blockIdx.x + 7 * blockIdx.y + 31 * blockIdx.z) & 7;
        atomicAdd(&ws[WS_STATS2 + cp * 2 * C2 + tid], sred[tid]);
    }
}

#define KC 512
#define KSUB 128
__global__ __launch_bounds__(256) void k_fconv(
    const float* __restrict__ pool, const float* __restrict__ ws,
    const float* __restrict__ g2, const float* __restrict__ bb2,
    const float* __restrict__ fw, float* __restrict__ feat)
{
    __shared__ float fwt[C2][KSUB + 1];
    __shared__ float x2t[NB][KSUB + 1];
    __shared__ float csh[2 * C2];
    if (threadIdx.x < C2) {
        int c = threadIdx.x;
        float s = 0.f, q = 0.f;
#pragma unroll
        for (int i = 0; i < 8; i++) {
            s += ws[WS_STATS2 + i * 2 * C2 + c];
            q += ws[WS_STATS2 + i * 2 * C2 + C2 + c];
        }
        const float N = (float)(NB * H1 * W1);
        float m = s / N;
        float v = q / N - m * m;
        float a = g2[c] / sqrtf(v + EPSV);
        csh[c] = a;
        csh[C2 + c] = bb2[c] - m * a;
    }
    int k0 = blockIdx.x * KC;
    int i = threadIdx.x / 16, j = threadIdx.x % 16;
    float acc[3][4] = {{0.f}};
    for (int sub = 0; sub < KC / KSUB; sub++) {
        int kb = k0 + sub * KSUB;
        __syncthreads();
        for (int li = threadIdx.x; li < C2 * KSUB; li += 256) {
            int o = li / KSUB, k = li % KSUB;
            fwt[o][k] = fw[o * 150528 + kb + k];
        }
        for (int li = threadIdx.x; li < NB * KSUB; li += 256) {
            int b = li / KSUB, k = li % KSUB;
            int kk = kb + k;
            int c = kk / (H2 * W2);
            float v = pool[b * 150528 + kk];
            x2t[b][k] = fmaxf(fmaf(v, csh[c], csh[C2 + c]), 0.f);
        }
        __syncthreads();
        for (int k = 0; k < KSUB; k++) {
            float fa[3], xv[4];
#pragma unroll
            for (int c = 0; c < 3; c++) fa[c] = fwt[i + 16 * c][k];
#pragma unroll
            for (int d = 0; d < 4; d++) xv[d] = x2t[j + 16 * d][k];
#pragma unroll
            for (int c = 0; c < 3; c++)
#pragma unroll
                for (int d = 0; d < 4; d++)
                    acc[c][d] = fmaf(fa[c], xv[d], acc[c][d]);
        }
    }
#pragma unroll
    for (int c = 0; c < 3; c++)
#pragma unroll
        for (int d = 0; d < 4; d++)
            atomicAdd(&feat[(j + 16 * d) * C2 + (i + 16 * c)], acc[c][d]);
}

__global__ __launch_bounds__(256) void k_sample(
    const float* __restrict__ x, const float* __restrict__ feat, const float* __restrict__ fcb,
    const float* __restrict__ l1w, const float* __restrict__ l1b,
    const float* __restrict__ l2w, const float* __restrict__ l2b,
    float* __restrict__ out)
{
    __shared__ float hsh[24];
    __shared__ float th[4];
    int b = blockIdx.y;
    int tid = threadIdx.x;
    if (tid < 24) {
        float a = l1b[tid];
        for (int o = 0; o < C2; o++)
            a = fmaf(feat[b * C2 + o] + fcb[o], l1w[tid * C2 + o], a);
        hsh[tid] = fmaxf(a, 0.f);
    }
    __syncthreads();
    if (tid < 4) {
        float a = l2b[tid];
        for (int jj = 0; jj < 24; jj++) a = fmaf(hsh[jj], l2w[tid * 24 + jj], a);
        th[tid] = a;
        if (blockIdx.x == 0) out[OUT0_ELEMS + tid * NB + b] = a;
    }
    __syncthreads();

    int idx = blockIdx.x * 256 + tid;
    int i = idx / W0, j = idx % W0;
    float tx = th[0], ty = th[1], sc = th[2], an = th[3];
    float cc = cosf(an), ss = sinf(an);
    float t00 = sc * cc, t01 = -sc * ss, t10 = sc * ss, t11 = sc * cc;
    float xs = (2.f * (float)j + 1.f) / (float)W0 - 1.f;
    float ys = (2.f * (float)i + 1.f) / (float)H0 - 1.f;
    float gx = t00 * xs + t01 * ys + tx;
    float gy = t10 * xs + t11 * ys + ty;
    float ix = ((gx + 1.f) * (float)W0 - 1.f) * 0.5f;
    float iy = ((gy + 1.f) * (float)H0 - 1.f) * 0.5f;
    float x0 = floorf(ix), y0 = floorf(iy);
    float x1f = x0 + 1.f, y1f = y0 + 1.f;
    float wx1 = ix - x0, wx0 = 1.f - wx1;
    float wy1 = iy - y0, wy0 = 1.f - wy1;
    const float* xb = x + b * (H0 * W0);
    auto tap = [&](float xf, float yf, float wgt) -> float {
        bool valid = (xf >= 0.f) & (xf < (float)W0) & (yf >= 0.f) & (yf < (float)H0);
        int xi = (int)fminf(fmaxf(xf, 0.f), (float)(W0 - 1));
        int yi = (int)fminf(fmaxf(yf, 0.f), (float)(H0 - 1));
        return valid ? xb[yi * W0 + xi] * wgt : 0.f;
    };
    float o = tap(x0, y0, wx0 * wy0) + tap(x1f, y0, wx1 * wy0)
            + tap(x0, y1f, wx0 * wy1) + tap(x1f, y1f, wx1 * wy1);
    out[(b * H0 + i) * W0 + j] = o;
}

extern "C" void kernel_launch(void* const* d_in, const int* in_sizes, int n_in,
                              void* d_out, int out_size, void* d_ws, size_t ws_size,
                              hipStream_t stream)
{
    const float* x    = (const float*)d_in[0];
    const float* c1w  = (const float*)d_in[1];
    const float* c1b  = (const float*)d_in[2];
    const float* bn1g = (const float*)d_in[3];
    const float* bn1b = (const float*)d_in[4];
    const float* c2w  = (const float*)d_in[5];
    const float* c2b  = (const float*)d_in[6];
    const float* bn2g = (const float*)d_in[7];
    const float* bn2b = (const float*)d_in[8];
    const float* fw   = (const float*)d_in[9];
    const float* fcb  = (const float*)d_in[10];
    const float* l1w  = (const float*)d_in[11];
    const float* l1b  = (const float*)d_in[12];
    const float* l2w  = (const float*)d_in[13];
    const float* l2b  = (const float*)d_in[14];
    float* ws  = (float*)d_ws;
    float* out = (float*)d_out;

    if (ws_size >= WS_NEED_BIG) {
        hipMemsetAsync(ws, 0, 432 * sizeof(float), stream);   // stats1 region
        // stats full-width tiles (896) + fw-transpose/prep (1176) in one launch
        k_stats_prep2<<<dim3(2072), 256, 0, stream>>>(
            x, c1w, c1b, c2w, fw, ws, (_Float16*)(ws + WS_X1), (_Float16*)(ws + WS_FWT));
        k_conv2_fused6<<<dim3(512), 256, 0, stream>>>(
            (const _Float16*)(ws + WS_X1), (const _Float16*)(ws + WS_B2),
            bn1g, bn1b, c2b, ws, (unsigned int*)(ws + WS_X2));
        k_fconv6<<<dim3(1176), 256, 0, stream>>>(
            (const unsigned int*)(ws + WS_X2), (const _Float16*)(ws + WS_FWT),
            ws, bn2g, bn2b, ws + WS_FEAT);
        k_sample4<<<dim3(98, 64), 256, 0, stream>>>(
            x, ws + WS_FEAT, fcb, l1w, l1b, l2w, l2b, out);
    } else {
        k_init<<<dim3(54), 256, 0, stream>>>(c2w, ws);
        k_conv1_stats<<<dim3(1024), 256, 0, stream>>>(x, c1w, c1b, ws);
        k_conv2_fused<<<dim3(7, 14, 64), 256, 0, stream>>>(
            x, c1w, c1b, bn1g, bn1b, (const _Float16*)(ws + WS_B2), c2b, ws, ws + WS_X2);
        k_fconv<<<dim3(150528 / KC), 256, 0, stream>>>(ws + WS_X2, ws, bn2g, bn2b, fw, ws + WS_FEAT);
        k_sample<<<dim3(196, 64), 256, 0, stream>>>(x, ws + WS_FEAT, fcb, l1w, l1b, l2w, l2b, out);
    }
}

// Round 14
// 218.010 us; speedup vs baseline: 1.1642x; 1.1642x over previous
//
#include <hip/hip_runtime.h>
#include <hip/hip_bf16.h>

#define NB 64
#define H0 224
#define W0 224
#define C1 24
#define C2 48
#define H1 112
#define W1 112
#define H2 56
#define W2 56
#define EPSV 1e-5f

// ws layout (float offsets)
#define WS_STATS1   0                       // 8 x (24+24) = 384
#define WS_STATS2   432                     // 8 x (48+48) = 768
#define WS_FEAT     1296                    // 64*48 = 3072
#define WS_B2       4368                    // 13824 fp16 = 6912 float slots (wave-linear w2 frags)
#define WS_X2       11280                   // pool_t fp16 k-blocked [2352 g][64 b][64]
#define WS_FWT      (WS_X2 + 4818944)       // fwt fp16 k-blocked [2352 g][48 o][64]
#define WS_X1       9645072                 // fp16 pooled PRE-BN conv1 max, ch-last [64][112][112][24]
#define WS_NEED_BIG ((size_t)(WS_X1 + 9633792) * 4)   // 77,115,456 B
#define OUT0_ELEMS  (NB*H0*W0)

typedef _Float16 v8h __attribute__((ext_vector_type(8)));   // 8 fp16 (4 VGPRs)
typedef float    v4f __attribute__((ext_vector_type(4)));   // MFMA acc / float4 loads

static __device__ __forceinline__ unsigned short f2h(float v) {
    _Float16 h = (_Float16)v;
    unsigned short us;
    __builtin_memcpy(&us, &h, 2);
    return us;
}

// ================= BIG-WS PATH =================
// K1 (merged, PROVEN R12): heterogeneous grid 3136+1176.
//  bid <  3136: conv1+pool+stats tile (stats4 body; weights in SGPRs; VGPR 48).
//  bid >= 3136: fw-transpose prep block; blocks p<54 additionally zero stats2/feat + build w2 frags.
__global__ __launch_bounds__(256) void k_stats_prep(
    const float* __restrict__ x, const float* __restrict__ w1, const float* __restrict__ b1,
    const float* __restrict__ w2, const float* __restrict__ fw,
    float* __restrict__ ws, _Float16* __restrict__ x1g, _Float16* __restrict__ fwt)
{
    __shared__ __align__(16) unsigned char smem[18432];
    const int tid = threadIdx.x;
    const int bid = blockIdx.x;

    if (bid >= 3136) {
        // -------- prep path --------
        _Float16 (*T)[136] = (_Float16(*)[136])smem;
        const int p = bid - 3136;                            // 0..1175
        if (p < 54) {
            int t = p * 256 + tid;
            if (t >= 432 && t < WS_B2) ws[t] = 0.f;          // zero stats2 + feat
            if (t < 13824) {
                int e = t & 7;
                int l = (t >> 3) & 63;
                int g = t >> 9;
                int q = l >> 4, ml = l & 15;
                int kp = g / 3, nt = g % 3;
                int ic = q * 8 + e;
                int oc = nt * 16 + ml;
                float v = (ic < C1) ? w2[(oc * C1 + ic) * 9 + kp] : 0.f;
                ((_Float16*)(ws + WS_B2))[t] = (_Float16)v;
            }
        }
        const int kb = p * 128;
#pragma unroll
        for (int t3 = 0; t3 < 6; t3++) {
            int li = tid + 256 * t3;
            int o = li >> 5, k4 = li & 31;
            float4 v = *(const float4*)&fw[(long)o * 150528 + kb + 4 * k4];
            T[o][4 * k4 + 0] = (_Float16)v.x;
            T[o][4 * k4 + 1] = (_Float16)v.y;
            T[o][4 * k4 + 2] = (_Float16)v.z;
            T[o][4 * k4 + 3] = (_Float16)v.w;
        }
        __syncthreads();
        uint4* dst = (uint4*)&fwt[(long)kb * 48];
#pragma unroll
        for (int t3 = 0; t3 < 3; t3++) {
            int u = tid + 256 * t3;
            int gg = u / 384;
            int rem = u % 384;
            int o = rem >> 3;
            int k8 = (rem & 7) * 8;
            dst[u] = *(const uint4*)&T[o][gg * 64 + k8];
        }
        return;
    }

    // -------- stats path --------
    float (*xt)[36] = (float(*)[36])smem;
    unsigned int (*outt)[13] = (unsigned int(*)[13])(smem + 4896);
    float* sred = (float*)(smem + 18208);

    const int b = bid / 49;
    const int rem0 = bid % 49;
    const int py0 = (rem0 / 7) * 16, px0 = (rem0 % 7) * 16;
    const int iy0 = 2 * py0 - 1, ix0 = 2 * px0 - 1;
    const float* xb = x + b * (H0 * W0);

    for (int li = tid; li < 34 * 34; li += 256) {
        int ry = li / 34, rx = li % 34;
        int gy = iy0 + ry, gx = ix0 + rx;
        bool ok = (gy >= 0) & (gy < H0) & (gx >= 0) & (gx < W0);
        xt[ry][rx] = ok ? xb[gy * W0 + gx] : 0.f;
    }

    const int wid = tid >> 6;
    const int lane = tid & 63;
    const int c0 = wid * 6;

    const int c0s = __builtin_amdgcn_readfirstlane(c0);
    const float* __restrict__ wps = w1 + c0s * 9;
    float wr[54], br[6];
#pragma unroll
    for (int k = 0; k < 54; k++) wr[k] = wps[k];
#pragma unroll
    for (int c = 0; c < 6; c++) br[c] = b1[c0s + c];

    __syncthreads();

    float s[6] = {0.f, 0.f, 0.f, 0.f, 0.f, 0.f};
    float q[6] = {0.f, 0.f, 0.f, 0.f, 0.f, 0.f};
    const int pc = lane & 15;
    const int pr0 = lane >> 4;

#pragma unroll
    for (int pp = 0; pp < 4; pp++) {
        const int pr = pr0 + 4 * pp;
        float patch[16];
#pragma unroll
        for (int i2 = 0; i2 < 4; i2++)
#pragma unroll
            for (int j2 = 0; j2 < 4; j2++)
                patch[i2 * 4 + j2] = xt[2 * pr + i2][2 * pc + j2];

        unsigned int pk[3];
#pragma unroll
        for (int cp = 0; cp < 3; cp++) {
            unsigned int pv = 0;
#pragma unroll
            for (int h = 0; h < 2; h++) {
                int c = 2 * cp + h;
                float m4 = -1e30f;
#pragma unroll
                for (int sy = 0; sy < 2; sy++)
#pragma unroll
                    for (int sx = 0; sx < 2; sx++) {
                        float a = br[c];
#pragma unroll
                        for (int ky = 0; ky < 3; ky++)
#pragma unroll
                            for (int kx = 0; kx < 3; kx++)
                                a = fmaf(patch[(sy + ky) * 4 + (sx + kx)], wr[c * 9 + ky * 3 + kx], a);
                        s[c] += a;
                        q[c] = fmaf(a, a, q[c]);
                        m4 = fmaxf(m4, a);
                    }
                pv |= ((unsigned int)f2h(m4)) << (16 * h);
            }
            pk[cp] = pv;
        }
        int pos = pr * 16 + pc;
        outt[pos][wid * 3 + 0] = pk[0];
        outt[pos][wid * 3 + 1] = pk[1];
        outt[pos][wid * 3 + 2] = pk[2];
    }

#pragma unroll
    for (int c = 0; c < 6; c++) {
#pragma unroll
        for (int off = 32; off > 0; off >>= 1) {
            s[c] += __shfl_down(s[c], off, 64);
            q[c] += __shfl_down(q[c], off, 64);
        }
    }
    if (lane == 0) {
#pragma unroll
        for (int c = 0; c < 6; c++) {
            sred[c0 + c] = s[c];
            sred[C1 + c0 + c] = q[c];
        }
    }
    __syncthreads();

    if (tid < 2 * C1) {
        atomicAdd(&ws[WS_STATS1 + (bid & 7) * 2 * C1 + tid], sred[tid]);
    }

    for (int u = tid; u < 768; u += 256) {
        int pos = u / 3, prt = u % 3;
        int pr = pos >> 4, pcc = pos & 15;
        long p = (long)(b * H1 + (py0 + pr)) * W1 + (px0 + pcc);
        uint4 v;
        v.x = outt[pos][4 * prt + 0];
        v.y = outt[pos][4 * prt + 1];
        v.z = outt[pos][4 * prt + 2];
        v.w = outt[pos][4 * prt + 3];
        *(uint4*)(x1g + p * C1 + prt * 8) = v;
    }
}

// K2 v6 (PROVEN R12): persistent conv2 MFMA, 16x16 tiles (4 rows/wave). B in 108 VGPRs;
// x1 dbuf LDS 2x18x18x32; BN2 stats in regs; pool_t fp16 k-blocked output. Grid 512.
__global__ __launch_bounds__(256, 2) void k_conv2_fused6(
    const _Float16* __restrict__ x1g, const _Float16* __restrict__ bpp,
    const float* __restrict__ g1, const float* __restrict__ bb1,
    const float* __restrict__ b2,
    float* __restrict__ ws, unsigned int* __restrict__ pooltu)
{
    __shared__ __align__(16) _Float16 x1t[2][18][18][32];
    __shared__ float alds[C1], bflds[C1];
    __shared__ float sred[2 * C2];

    const int tid = threadIdx.x;
    const int w = tid >> 6;
    const int lane = tid & 63;
    const int ml = lane & 15;
    const int qq = lane >> 4;

    v8h B[9][3];
#pragma unroll
    for (int kp = 0; kp < 9; kp++)
#pragma unroll
        for (int nt = 0; nt < 3; nt++)
            B[kp][nt] = *(const v8h*)&bpp[((kp * 3 + nt) * 64 + lane) * 8];

    if (tid < C1) {
        float s = 0.f, q = 0.f;
#pragma unroll
        for (int i = 0; i < 8; i++) {
            s += ws[WS_STATS1 + i * 2 * C1 + tid];
            q += ws[WS_STATS1 + i * 2 * C1 + C1 + tid];
        }
        const float N = (float)(NB * H0 * W0);
        float m = s / N;
        float v = q / N - m * m;
        float a = g1[tid] / sqrtf(v + EPSV);
        alds[tid] = a;
        bflds[tid] = bb1[tid] - m * a;
    }
    if (tid < 2 * C2) sred[tid] = 0.f;

    {
        v8h z8;
#pragma unroll
        for (int e = 0; e < 8; e++) z8[e] = (_Float16)0.f;
        for (int li = tid; li < 2 * 18 * 18; li += 256) {
            int bu = li / 324, pos = li % 324;
            *(v8h*)&x1t[bu][pos / 18][pos % 18][24] = z8;
        }
    }

    float bias[3] = {b2[ml], b2[16 + ml], b2[32 + ml]};

    int spart[4], spr[4], spc[4]; bool sv[4];
#pragma unroll
    for (int s4 = 0; s4 < 4; s4++) {
        int li = tid + s4 * 256;
        sv[s4] = li < 972;
        int part = li % 3;
        int pos = li / 3;
        spart[s4] = part;
        spr[s4] = pos / 18;
        spc[s4] = pos % 18;
    }

    const int nb = gridDim.x;
    const int NTILE = 3136;
    int qn = NTILE / nb, rn = NTILE % nb;
    int start = (blockIdx.x < rn) ? blockIdx.x * (qn + 1)
                                  : rn * (qn + 1) + (blockIdx.x - rn) * qn;
    int cnt = (blockIdx.x < rn) ? qn + 1 : qn;

    float svacc[3] = {0.f, 0.f, 0.f}, qvacc[3] = {0.f, 0.f, 0.f};

    v8h raw[4];
    bool inb_n[4];
    {
        int t = start;
        int tb = t / 49, rem = t % 49;
        int ty = (rem / 7) * 16, txx = (rem % 7) * 16;
#pragma unroll
        for (int s4 = 0; s4 < 4; s4++) {
#pragma unroll
            for (int e = 0; e < 8; e++) raw[s4][e] = (_Float16)0.f;
            int gy = ty - 1 + spr[s4], gx = txx - 1 + spc[s4];
            inb_n[s4] = sv[s4] & (gy >= 0) & (gy < H1) & (gx >= 0) & (gx < W1);
            if (inb_n[s4])
                raw[s4] = *(const v8h*)&x1g[((tb * H1 + gy) * W1 + gx) * C1 + spart[s4] * 8];
        }
    }
    __syncthreads();

#pragma unroll
    for (int s4 = 0; s4 < 4; s4++) {
        if (sv[s4]) {
            v8h r8;
            if (inb_n[s4]) {
#pragma unroll
                for (int e = 0; e < 8; e++) {
                    int c = spart[s4] * 8 + e;
                    float vv = fmaxf(fmaf((float)raw[s4][e], alds[c], bflds[c]), 0.f);
                    r8[e] = (_Float16)vv;
                }
            } else {
#pragma unroll
                for (int e = 0; e < 8; e++) r8[e] = (_Float16)0.f;
            }
            *(v8h*)&x1t[0][spr[s4]][spc[s4]][spart[s4] * 8] = r8;
        }
    }
    __syncthreads();

    for (int it = 0; it < cnt; it++) {
        const int cur = it & 1;
        const int t = start + it;
        const int tb = t / 49, rem = t % 49;
        const int ty = (rem / 7) * 16, txx = (rem % 7) * 16;

        const bool haveNext = (it + 1 < cnt);
        if (haveNext) {
            int t2 = t + 1;
            int nb2 = t2 / 49, rem2 = t2 % 49;
            int ny = (rem2 / 7) * 16, nx = (rem2 % 7) * 16;
#pragma unroll
            for (int s4 = 0; s4 < 4; s4++) {
#pragma unroll
                for (int e = 0; e < 8; e++) raw[s4][e] = (_Float16)0.f;
                int gy = ny - 1 + spr[s4], gx = nx - 1 + spc[s4];
                inb_n[s4] = sv[s4] & (gy >= 0) & (gy < H1) & (gx >= 0) & (gx < W1);
                if (inb_n[s4])
                    raw[s4] = *(const v8h*)&x1g[((nb2 * H1 + gy) * W1 + gx) * C1 + spart[s4] * 8];
            }
        }

        v4f acc[4][3];
#pragma unroll
        for (int mt = 0; mt < 4; mt++)
#pragma unroll
            for (int nt = 0; nt < 3; nt++)
                acc[mt][nt] = (v4f){0.f, 0.f, 0.f, 0.f};

#pragma unroll
        for (int kp = 0; kp < 9; kp++) {
            const int ky = kp / 3, kx = kp % 3;
#pragma unroll
            for (int mt = 0; mt < 4; mt++) {
                const int r = 4 * w + mt;
                v8h a = *(const v8h*)&x1t[cur][r + ky][ml + kx][qq * 8];
                acc[mt][0] = __builtin_amdgcn_mfma_f32_16x16x32_f16(a, B[kp][0], acc[mt][0], 0, 0, 0);
                acc[mt][1] = __builtin_amdgcn_mfma_f32_16x16x32_f16(a, B[kp][1], acc[mt][1], 0, 0, 0);
                acc[mt][2] = __builtin_amdgcn_mfma_f32_16x16x32_f16(a, B[kp][2], acc[mt][2], 0, 0, 0);
            }
        }

#pragma unroll
        for (int nt = 0; nt < 3; nt++) {
            int oc = nt * 16 + ml;
            float z[4][4];
#pragma unroll
            for (int mt = 0; mt < 4; mt++)
#pragma unroll
                for (int rg = 0; rg < 4; rg++) {
                    float val = acc[mt][nt][rg] + bias[nt];
                    z[mt][rg] = val;
                    svacc[nt] += val;
                    qvacc[nt] = fmaf(val, val, qvacc[nt]);
                }
#pragma unroll
            for (int h = 0; h < 2; h++) {
                int py = (ty >> 1) + 2 * w + h;
                float m0 = fmaxf(fmaxf(z[2 * h][0], z[2 * h][1]),
                                 fmaxf(z[2 * h + 1][0], z[2 * h + 1][1]));
                float m1 = fmaxf(fmaxf(z[2 * h][2], z[2 * h][3]),
                                 fmaxf(z[2 * h + 1][2], z[2 * h + 1][3]));
                int px0 = (txx >> 1) + qq * 2;
                int k = oc * 3136 + py * W2 + px0;
                unsigned int pk2 = (unsigned int)f2h(m0) | ((unsigned int)f2h(m1) << 16);
                pooltu[(((k >> 6) * NB + tb) << 5) + ((k & 63) >> 1)] = pk2;
            }
        }

        if (haveNext) {
#pragma unroll
            for (int s4 = 0; s4 < 4; s4++) {
                if (sv[s4]) {
                    v8h r8;
                    if (inb_n[s4]) {
#pragma unroll
                        for (int e = 0; e < 8; e++) {
                            int c = spart[s4] * 8 + e;
                            float vv = fmaxf(fmaf((float)raw[s4][e], alds[c], bflds[c]), 0.f);
                            r8[e] = (_Float16)vv;
                        }
                    } else {
#pragma unroll
                        for (int e = 0; e < 8; e++) r8[e] = (_Float16)0.f;
                    }
                    *(v8h*)&x1t[cur ^ 1][spr[s4]][spc[s4]][spart[s4] * 8] = r8;
                }
            }
        }
        __syncthreads();
    }

#pragma unroll
    for (int nt = 0; nt < 3; nt++) {
        float sv2 = svacc[nt], qv = qvacc[nt];
        sv2 += __shfl_xor(sv2, 16, 64); qv += __shfl_xor(qv, 16, 64);
        sv2 += __shfl_xor(sv2, 32, 64); qv += __shfl_xor(qv, 32, 64);
        if (qq == 0) {
            atomicAdd(&sred[nt * 16 + ml], sv2);
            atomicAdd(&sred[C2 + nt * 16 + ml], qv);
        }
    }
    __syncthreads();
    if (tid < 2 * C2) {
        atomicAdd(&ws[WS_STATS2 + (blockIdx.x & 7) * 2 * C2 + tid], sred[tid]);
    }
}

// K3 v6 (PROVEN): MFMA fconv on linear fp16 streams; atomicAdd directly into feat.
__global__ __launch_bounds__(256) void k_fconv6(
    const unsigned int* __restrict__ pooltu, const _Float16* __restrict__ fwt,
    const float* __restrict__ ws, const float* __restrict__ g2, const float* __restrict__ bb2,
    float* __restrict__ feat)
{
    __shared__ __align__(16) _Float16 fwh[48][136];
    __shared__ __align__(16) _Float16 x2h[64][136];
    __shared__ float csh[2 * C2];

    const int tid = threadIdx.x;
    const int bx = blockIdx.x;

    const uint4* fsrc = (const uint4*)fwt + (long)bx * 768;
    const uint4* psrc = (const uint4*)pooltu + (long)bx * 1024;
    uint4 fr[3], pr[4];
#pragma unroll
    for (int t3 = 0; t3 < 3; t3++) fr[t3] = fsrc[tid + 256 * t3];
#pragma unroll
    for (int t4 = 0; t4 < 4; t4++) pr[t4] = psrc[tid + 256 * t4];

    if (tid < C2) {
        int c = tid;
        float s = 0.f, q = 0.f;
#pragma unroll
        for (int i = 0; i < 8; i++) {
            s += ws[WS_STATS2 + i * 2 * C2 + c];
            q += ws[WS_STATS2 + i * 2 * C2 + C2 + c];
        }
        const float N = (float)(NB * H1 * W1);
        float m = s / N;
        float v = q / N - m * m;
        float a = g2[c] / sqrtf(v + EPSV);
        csh[c] = a;
        csh[C2 + c] = bb2[c] - m * a;
    }
    __syncthreads();

#pragma unroll
    for (int t3 = 0; t3 < 3; t3++) {
        int li = tid + 256 * t3;
        int gg = li / 384;
        int o = (li % 384) / 8;
        int kin = (li & 7) * 8;
        *(uint4*)&fwh[o][gg * 64 + kin] = fr[t3];
    }
    const int c0 = (2 * bx) / 49, c1 = (2 * bx + 1) / 49;
    const float a0 = csh[c0], bf0 = csh[C2 + c0];
    const float a1 = csh[c1], bf1 = csh[C2 + c1];
#pragma unroll
    for (int t4 = 0; t4 < 4; t4++) {
        int li = tid + 256 * t4;
        int gg = li >> 9;
        int b = (li & 511) >> 3;
        int kin = (li & 7) * 8;
        float aa = gg ? a1 : a0;
        float bb = gg ? bf1 : bf0;
        union { uint4 u; v8h h; } cv;
        cv.u = pr[t4];
        v8h r8;
#pragma unroll
        for (int e = 0; e < 8; e++)
            r8[e] = (_Float16)fmaxf(fmaf((float)cv.h[e], aa, bb), 0.f);
        *(v8h*)&x2h[b][gg * 64 + kin] = r8;
    }
    __syncthreads();

    const int w = tid >> 6;
    const int lane = tid & 63;
    const int ml = lane & 15;
    const int qq = lane >> 4;

    v4f acc[3];
#pragma unroll
    for (int ot = 0; ot < 3; ot++) acc[ot] = (v4f){0.f, 0.f, 0.f, 0.f};

#pragma unroll
    for (int ks = 0; ks < 4; ks++) {
        v8h a = *(const v8h*)&x2h[w * 16 + ml][ks * 32 + qq * 8];
#pragma unroll
        for (int ot = 0; ot < 3; ot++) {
            v8h bb = *(const v8h*)&fwh[ot * 16 + ml][ks * 32 + qq * 8];
            acc[ot] = __builtin_amdgcn_mfma_f32_16x16x32_f16(a, bb, acc[ot], 0, 0, 0);
        }
    }

#pragma unroll
    for (int ot = 0; ot < 3; ot++)
#pragma unroll
        for (int rg = 0; rg < 4; rg++)
            atomicAdd(&feat[(w * 16 + qq * 4 + rg) * C2 + ot * 16 + ml], acc[ot][rg]);
}

// K4 (merged head, PROVEN): grid_sample with wave-local head.
__global__ __launch_bounds__(256) void k_sample4(
    const float* __restrict__ x, const float* __restrict__ feat, const float* __restrict__ fcb,
    const float* __restrict__ l1w, const float* __restrict__ l1b,
    const float* __restrict__ l2w, const float* __restrict__ l2b,
    float* __restrict__ out)
{
    __shared__ float hsh[24];
    __shared__ float th[4];
    const int b = blockIdx.y;
    const int tid = threadIdx.x;
    if (tid < 24) {
        float a = l1b[tid];
#pragma unroll
        for (int o = 0; o < C2; o++)
            a = fmaf(feat[b * C2 + o] + fcb[o], l1w[tid * C2 + o], a);
        hsh[tid] = fmaxf(a, 0.f);
    }
    __syncthreads();
    if (tid < 4) {
        float a = l2b[tid];
#pragma unroll
        for (int jj = 0; jj < 24; jj++) a = fmaf(hsh[jj], l2w[tid * 24 + jj], a);
        th[tid] = a;
        if (blockIdx.x == 0) out[OUT0_ELEMS + tid * NB + b] = a;
    }
    __syncthreads();

    const float tx = th[0], ty = th[1], sc = th[2], an = th[3];
    const float cc = cosf(an), ss = sinf(an);
    const float t00 = sc * cc, t01 = -sc * ss, t10 = sc * ss, t11 = sc * cc;
    const float* xb = x + b * (H0 * W0);

    int idx = (blockIdx.x * 256 + tid) * 2;
    int i = idx / W0, j = idx % W0;
    float ys = (2.f * (float)i + 1.f) / (float)H0 - 1.f;

    float o2[2];
#pragma unroll
    for (int px = 0; px < 2; px++) {
        float xs = (2.f * (float)(j + px) + 1.f) / (float)W0 - 1.f;
        float gx = t00 * xs + t01 * ys + tx;
        float gy = t10 * xs + t11 * ys + ty;
        float ix = ((gx + 1.f) * (float)W0 - 1.f) * 0.5f;
        float iy = ((gy + 1.f) * (float)H0 - 1.f) * 0.5f;
        float x0 = floorf(ix), y0 = floorf(iy);
        float x1f = x0 + 1.f, y1f = y0 + 1.f;
        float wx1 = ix - x0, wx0 = 1.f - wx1;
        float wy1 = iy - y0, wy0 = 1.f - wy1;
        auto tap = [&](float xf, float yf, float wgt) -> float {
            bool valid = (xf >= 0.f) & (xf < (float)W0) & (yf >= 0.f) & (yf < (float)H0);
            int xi = (int)fminf(fmaxf(xf, 0.f), (float)(W0 - 1));
            int yi = (int)fminf(fmaxf(yf, 0.f), (float)(H0 - 1));
            return valid ? xb[yi * W0 + xi] * wgt : 0.f;
        };
        o2[px] = tap(x0, y0, wx0 * wy0) + tap(x1f, y0, wx1 * wy0)
               + tap(x0, y1f, wx0 * wy1) + tap(x1f, y1f, wx1 * wy1);
    }
    *(float2*)&out[(b * H0 + i) * W0 + j] = make_float2(o2[0], o2[1]);
}

// ================= OLD PROVEN PATH (fallback if ws too small) =================
__global__ __launch_bounds__(256) void k_init(const float* __restrict__ w2, float* __restrict__ ws)
{
    int t = blockIdx.x * 256 + threadIdx.x;
    if (t < WS_B2) ws[t] = 0.f;
    if (t < 13824) {
        int e = t & 7;
        int l = (t >> 3) & 63;
        int g = t >> 9;
        int q = l >> 4, ml = l & 15;
        int kp = g / 3, nt = g % 3;
        int ic = q * 8 + e;
        int oc = nt * 16 + ml;
        float v = (ic < C1) ? w2[(oc * C1 + ic) * 9 + kp] : 0.f;
        ((_Float16*)(ws + WS_B2))[t] = (_Float16)v;
    }
}

__global__ __launch_bounds__(256) void k_conv1_stats(
    const float* __restrict__ x, const float* __restrict__ w1, const float* __restrict__ b1,
    float* __restrict__ ws)
{
    float s[C1], q[C1];
#pragma unroll
    for (int c = 0; c < C1; c++) { s[c] = 0.f; q[c] = 0.f; }
    const int NT = gridDim.x * 256;
    const int total = NB * H0 * W0;
    for (int p = blockIdx.x * 256 + threadIdx.x; p < total; p += NT) {
        int b = p / (H0 * W0);
        int r = p % (H0 * W0);
        int y = r / W0;
        int xx = r % W0;
        const float* xb = x + b * (H0 * W0);
        float patch[9];
#pragma unroll
        for (int dy = 0; dy < 3; dy++)
#pragma unroll
            for (int dx = 0; dx < 3; dx++) {
                int yy = y + dy - 1, xc = xx + dx - 1;
                bool ok = (yy >= 0) & (yy < H0) & (xc >= 0) & (xc < W0);
                patch[dy * 3 + dx] = ok ? xb[yy * W0 + xc] : 0.f;
            }
#pragma unroll
        for (int c = 0; c < C1; c++) {
            const float* wp = w1 + c * 9;
            float a = b1[c];
#pragma unroll
            for (int k = 0; k < 9; k++) a = fmaf(patch[k], wp[k], a);
            s[c] += a;
            q[c] = fmaf(a, a, q[c]);
        }
    }
#pragma unroll
    for (int c = 0; c < C1; c++) {
#pragma unroll
        for (int off = 32; off > 0; off >>= 1) {
            s[c] += __shfl_down(s[c], off, 64);
            q[c] += __shfl_down(q[c], off, 64);
        }
    }
    __shared__ float sred[2 * C1];
    if (threadIdx.x < 2 * C1) sred[threadIdx.x] = 0.f;
    __syncthreads();
    if ((threadIdx.x & 63) == 0) {
#pragma unroll
        for (int c = 0; c < C1; c++) {
            atomicAdd(&sred[c], s[c]);
            atomicAdd(&sred[C1 + c], q[c]);
        }
    }
    __syncthreads();
    if (threadIdx.x < 2 * C1) {
        atomicAdd(&ws[WS_STATS1 + (blockIdx.x & 7) * 2 * C1 + threadIdx.x], sred[threadIdx.x]);
    }
}

__global__ __launch_bounds__(256, 2) void k_conv2_fused(
    const float* __restrict__ x, const float* __restrict__ w1, const float* __restrict__ b1,
    const float* __restrict__ g1, const float* __restrict__ bb1,
    const _Float16* __restrict__ bpp, const float* __restrict__ b2,
    float* __restrict__ ws, float* __restrict__ pool)
{
    __shared__ float xt[22][38];
    __shared__ __align__(16) _Float16 x1t[10][18][32];
    __shared__ __align__(16) _Float16 Blds[13824];
    __shared__ float wlds[C1 * 9];
    __shared__ float blds[C1], alds[C1], bflds[C1];
    __shared__ float sred[2 * C2];

    const int tid = threadIdx.x;
    const int b = blockIdx.z;
    const int y0 = blockIdx.y * 8;
    const int x0 = blockIdx.x * 16;
    const float* xb = x + b * (H0 * W0);

    for (int li = tid; li < 13824 / 8; li += 256)
        ((uint4*)Blds)[li] = ((const uint4*)bpp)[li];

    if (tid < C1 * 9) wlds[tid] = w1[tid];
    if (tid < C1) {
        float s = 0.f, q = 0.f;
#pragma unroll
        for (int i = 0; i < 8; i++) {
            s += ws[WS_STATS1 + i * 2 * C1 + tid];
            q += ws[WS_STATS1 + i * 2 * C1 + C1 + tid];
        }
        const float N = (float)(NB * H0 * W0);
        float m = s / N;
        float v = q / N - m * m;
        float a = g1[tid] / sqrtf(v + EPSV);
        blds[tid] = b1[tid];
        alds[tid] = a;
        bflds[tid] = bb1[tid] - m * a;
    }
    if (tid < 2 * C2) sred[tid] = 0.f;

    const int oy0 = 2 * y0 - 3, ox0 = 2 * x0 - 3;
    for (int li = tid; li < 22 * 38; li += 256) {
        int ry = li / 38, rx = li % 38;
        int gy = oy0 + ry, gx = ox0 + rx;
        bool ok = (gy >= 0) & (gy < H0) & (gx >= 0) & (gx < W0);
        xt[ry][rx] = ok ? xb[gy * W0 + gx] : 0.f;
    }
    __syncthreads();

    if (tid < 180) {
        int pr = tid / 18, pc = tid % 18;
        int gy = y0 - 1 + pr, gx = x0 - 1 + pc;
        bool valid = (gy >= 0) & (gy < H1) & (gx >= 0) & (gx < W1);
        float patch[16];
#pragma unroll
        for (int dy = 0; dy < 4; dy++)
#pragma unroll
            for (int dx = 0; dx < 4; dx++)
                patch[dy * 4 + dx] = xt[2 * pr + dy][2 * pc + dx];
        unsigned int* dst = (unsigned int*)&x1t[pr][pc][0];
#pragma unroll
        for (int cp = 0; cp < 12; cp++) {
            unsigned int pk = 0;
#pragma unroll
            for (int h = 0; h < 2; h++) {
                int c = 2 * cp + h;
                float m4 = -1e30f;
#pragma unroll
                for (int py = 0; py < 2; py++)
#pragma unroll
                    for (int px = 0; px < 2; px++) {
                        float a = blds[c];
#pragma unroll
                        for (int ky = 0; ky < 3; ky++)
#pragma unroll
                            for (int kx = 0; kx < 3; kx++)
                                a = fmaf(patch[(py + ky) * 4 + (px + kx)], wlds[c * 9 + ky * 3 + kx], a);
                        m4 = fmaxf(m4, fmaf(a, alds[c], bflds[c]));
                    }
                float v = valid ? fmaxf(m4, 0.f) : 0.f;
                pk |= ((unsigned int)f2h(v)) << (16 * h);
            }
            dst[cp] = pk;
        }
        dst[12] = 0; dst[13] = 0; dst[14] = 0; dst[15] = 0;
    }
    __syncthreads();

    const int w = tid >> 6;
    const int lane = tid & 63;
    const int ml = lane & 15;
    const int q = lane >> 4;

    v4f acc[2][3];
#pragma unroll
    for (int mt = 0; mt < 2; mt++)
#pragma unroll
        for (int nt = 0; nt < 3; nt++)
            acc[mt][nt] = (v4f){0.f, 0.f, 0.f, 0.f};

#pragma unroll
    for (int kp = 0; kp < 9; kp++) {
        const int ky = kp / 3, kx = kp % 3;
        v8h B0 = *(const v8h*)&Blds[((kp * 3 + 0) * 64 + lane) * 8];
        v8h B1 = *(const v8h*)&Blds[((kp * 3 + 1) * 64 + lane) * 8];
        v8h B2 = *(const v8h*)&Blds[((kp * 3 + 2) * 64 + lane) * 8];
#pragma unroll
        for (int mt = 0; mt < 2; mt++) {
            const int r = 2 * w + mt;
            v8h a = *(const v8h*)&x1t[r + ky][ml + kx][q * 8];
            acc[mt][0] = __builtin_amdgcn_mfma_f32_16x16x32_f16(a, B0, acc[mt][0], 0, 0, 0);
            acc[mt][1] = __builtin_amdgcn_mfma_f32_16x16x32_f16(a, B1, acc[mt][1], 0, 0, 0);
            acc[mt][2] = __builtin_amdgcn_mfma_f32_16x16x32_f16(a, B2, acc[mt][2], 0, 0, 0);
        }
    }

#pragma unroll
    for (int nt = 0; nt < 3; nt++) {
        int oc = nt * 16 + ml;
        float bias = b2[oc];
        float z[2][4];
        float sv = 0.f, qv = 0.f;
#pragma unroll
        for (int mt = 0; mt < 2; mt++)
#pragma unroll
            for (int rg = 0; rg < 4; rg++) {
                float val = acc[mt][nt][rg] + bias;
                z[mt][rg] = val;
                sv += val;
                qv = fmaf(val, val, qv);
            }
        sv += __shfl_xor(sv, 16, 64); qv += __shfl_xor(qv, 16, 64);
        sv += __shfl_xor(sv, 32, 64); qv += __shfl_xor(qv, 32, 64);
        if (q == 0) { atomicAdd(&sred[oc], sv); atomicAdd(&sred[C2 + oc], qv); }

        int py = (y0 >> 1) + w;
#pragma unroll
        for (int j = 0; j < 2; j++) {
            float m = fmaxf(fmaxf(z[0][2 * j], z[0][2 * j + 1]),
                            fmaxf(z[1][2 * j], z[1][2 * j + 1]));
            int px = (x0 >> 1) + q * 2 + j;
            pool[((b * C2 + oc) * H2 + py) * W2 + px] = m;
        }
    }
    __syncthreads();
    if (tid < 2 * C2) {
        int cp = (blockIdx.x + 7 * blockIdx.y + 31 * blockIdx.z) & 7;
        atomicAdd(&ws[WS_STATS2 + cp * 2 * C2 + tid], sred[tid]);
    }
}

#define KC 512
#define KSUB 128
__global__ __launch_bounds__(256) void k_fconv(
    const float* __restrict__ pool, const float* __restrict__ ws,
    const float* __restrict__ g2, const float* __restrict__ bb2,
    const float* __restrict__ fw, float* __restrict__ feat)
{
    __shared__ float fwt[C2][KSUB + 1];
    __shared__ float x2t[NB][KSUB + 1];
    __shared__ float csh[2 * C2];
    if (threadIdx.x < C2) {
        int c = threadIdx.x;
        float s = 0.f, q = 0.f;
#pragma unroll
        for (int i = 0; i < 8; i++) {
            s += ws[WS_STATS2 + i * 2 * C2 + c];
            q += ws[WS_STATS2 + i * 2 * C2 + C2 + c];
        }
        const float N = (float)(NB * H1 * W1);
        float m = s / N;
        float v = q / N - m * m;
        float a = g2[c] / sqrtf(v + EPSV);
        csh[c] = a;
        csh[C2 + c] = bb2[c] - m * a;
    }
    int k0 = blockIdx.x * KC;
    int i = threadIdx.x / 16, j = threadIdx.x % 16;
    float acc[3][4] = {{0.f}};
    for (int sub = 0; sub < KC / KSUB; sub++) {
        int kb = k0 + sub * KSUB;
        __syncthreads();
        for (int li = threadIdx.x; li < C2 * KSUB; li += 256) {
            int o = li / KSUB, k = li % KSUB;
            fwt[o][k] = fw[o * 150528 + kb + k];
        }
        for (int li = threadIdx.x; li < NB * KSUB; li += 256) {
            int b = li / KSUB, k = li % KSUB;
            int kk = kb + k;
            int c = kk / (H2 * W2);
            float v = pool[b * 150528 + kk];
            x2t[b][k] = fmaxf(fmaf(v, csh[c], csh[C2 + c]), 0.f);
        }
        __syncthreads();
        for (int k = 0; k < KSUB; k++) {
            float fa[3], xv[4];
#pragma unroll
            for (int c = 0; c < 3; c++) fa[c] = fwt[i + 16 * c][k];
#pragma unroll
            for (int d = 0; d < 4; d++) xv[d] = x2t[j + 16 * d][k];
#pragma unroll
            for (int c = 0; c < 3; c++)
#pragma unroll
                for (int d = 0; d < 4; d++)
                    acc[c][d] = fmaf(fa[c], xv[d], acc[c][d]);
        }
    }
#pragma unroll
    for (int c = 0; c < 3; c++)
#pragma unroll
        for (int d = 0; d < 4; d++)
            atomicAdd(&feat[(j + 16 * d) * C2 + (i + 16 * c)], acc[c][d]);
}

__global__ __launch_bounds__(256) void k_sample(
    const float* __restrict__ x, const float* __restrict__ feat, const float* __restrict__ fcb,
    const float* __restrict__ l1w, const float* __restrict__ l1b,
    const float* __restrict__ l2w, const float* __restrict__ l2b,
    float* __restrict__ out)
{
    __shared__ float hsh[24];
    __shared__ float th[4];
    int b = blockIdx.y;
    int tid = threadIdx.x;
    if (tid < 24) {
        float a = l1b[tid];
        for (int o = 0; o < C2; o++)
            a = fmaf(feat[b * C2 + o] + fcb[o], l1w[tid * C2 + o], a);
        hsh[tid] = fmaxf(a, 0.f);
    }
    __syncthreads();
    if (tid < 4) {
        float a = l2b[tid];
        for (int jj = 0; jj < 24; jj++) a = fmaf(hsh[jj], l2w[tid * 24 + jj], a);
        th[tid] = a;
        if (blockIdx.x == 0) out[OUT0_ELEMS + tid * NB + b] = a;
    }
    __syncthreads();

    int idx = blockIdx.x * 256 + tid;
    int i = idx / W0, j = idx % W0;
    float tx = th[0], ty = th[1], sc = th[2], an = th[3];
    float cc = cosf(an), ss = sinf(an);
    float t00 = sc * cc, t01 = -sc * ss, t10 = sc * ss, t11 = sc * cc;
    float xs = (2.f * (float)j + 1.f) / (float)W0 - 1.f;
    float ys = (2.f * (float)i + 1.f) / (float)H0 - 1.f;
    float gx = t00 * xs + t01 * ys + tx;
    float gy = t10 * xs + t11 * ys + ty;
    float ix = ((gx + 1.f) * (float)W0 - 1.f) * 0.5f;
    float iy = ((gy + 1.f) * (float)H0 - 1.f) * 0.5f;
    float x0 = floorf(ix), y0 = floorf(iy);
    float x1f = x0 + 1.f, y1f = y0 + 1.f;
    float wx1 = ix - x0, wx0 = 1.f - wx1;
    float wy1 = iy - y0, wy0 = 1.f - wy1;
    const float* xb = x + b * (H0 * W0);
    auto tap = [&](float xf, float yf, float wgt) -> float {
        bool valid = (xf >= 0.f) & (xf < (float)W0) & (yf >= 0.f) & (yf < (float)H0);
        int xi = (int)fminf(fmaxf(xf, 0.f), (float)(W0 - 1));
        int yi = (int)fminf(fmaxf(yf, 0.f), (float)(H0 - 1));
        return valid ? xb[yi * W0 + xi] * wgt : 0.f;
    };
    float o = tap(x0, y0, wx0 * wy0) + tap(x1f, y0, wx1 * wy0)
            + tap(x0, y1f, wx0 * wy1) + tap(x1f, y1f, wx1 * wy1);
    out[(b * H0 + i) * W0 + j] = o;
}

extern "C" void kernel_launch(void* const* d_in, const int* in_sizes, int n_in,
                              void* d_out, int out_size, void* d_ws, size_t ws_size,
                              hipStream_t stream)
{
    const float* x    = (const float*)d_in[0];
    const float* c1w  = (const float*)d_in[1];
    const float* c1b  = (const float*)d_in[2];
    const float* bn1g = (const float*)d_in[3];
    const float* bn1b = (const float*)d_in[4];
    const float* c2w  = (const float*)d_in[5];
    const float* c2b  = (const float*)d_in[6];
    const float* bn2g = (const float*)d_in[7];
    const float* bn2b = (const float*)d_in[8];
    const float* fw   = (const float*)d_in[9];
    const float* fcb  = (const float*)d_in[10];
    const float* l1w  = (const float*)d_in[11];
    const float* l1b  = (const float*)d_in[12];
    const float* l2w  = (const float*)d_in[13];
    const float* l2b  = (const float*)d_in[14];
    float* ws  = (float*)d_ws;
    float* out = (float*)d_out;

    if (ws_size >= WS_NEED_BIG) {
        hipMemsetAsync(ws, 0, 432 * sizeof(float), stream);   // stats1 region
        k_stats_prep<<<dim3(4312), 256, 0, stream>>>(
            x, c1w, c1b, c2w, fw, ws, (_Float16*)(ws + WS_X1), (_Float16*)(ws + WS_FWT));
        k_conv2_fused6<<<dim3(512), 256, 0, stream>>>(
            (const _Float16*)(ws + WS_X1), (const _Float16*)(ws + WS_B2),
            bn1g, bn1b, c2b, ws, (unsigned int*)(ws + WS_X2));
        k_fconv6<<<dim3(1176), 256, 0, stream>>>(
            (const unsigned int*)(ws + WS_X2), (const _Float16*)(ws + WS_FWT),
            ws, bn2g, bn2b, ws + WS_FEAT);
        k_sample4<<<dim3(98, 64), 256, 0, stream>>>(
            x, ws + WS_FEAT, fcb, l1w, l1b, l2w, l2b, out);
    } else {
        k_init<<<dim3(54), 256, 0, stream>>>(c2w, ws);
        k_conv1_stats<<<dim3(1024), 256, 0, stream>>>(x, c1w, c1b, ws);
        k_conv2_fused<<<dim3(7, 14, 64), 256, 0, stream>>>(
            x, c1w, c1b, bn1g, bn1b, (const _Float16*)(ws + WS_B2), c2b, ws, ws + WS_X2);
        k_fconv<<<dim3(150528 / KC), 256, 0, stream>>>(ws + WS_X2, ws, bn2g, bn2b, fw, ws + WS_FEAT);
        k_sample<<<dim3(196, 64), 256, 0, stream>>>(x, ws + WS_FEAT, fcb, l1w, l1b, l2w, l2b, out);
    }
}